// Round 1
// baseline (6600.574 us; speedup 1.0000x reference)
//
#include <hip/hip_runtime.h>
#include <math.h>

typedef float f4 __attribute__((ext_vector_type(4)));

#define TM 128
#define TN 128
#define TK 32
#define BSTRIDE (TN + 4)   // pad Bs rows by 4 words to spread write banks

// ---------------- workspace layout (floats) ----------------
// h1 : 256*15*15*256 = 14,745,600   (also reused as d2)
// h2 : 256*14*14*512 = 25,690,112   (also reused as d1)
// fn : 43264
// cn : 128
// idx: 43264 (int)
// pa : 2048 doubles, pb : 2048 doubles  (= 8192 floats)
#define H1_F 14745600L
#define H2_F 25690112L
#define WS_FLOATS 40540000L

__device__ float g_fallback[WS_FLOATS];

__device__ __forceinline__ f4 ldg4(const float* p) { return *(const f4*)p; }

// ============================================================
// Implicit-GEMM conv / convT.  out[b,oi,oj,co] =
//   sum_{di,dj,ci} in[b, oi+di+off, oj+dj+off, ci] * w[di,dj,ci,co]
// off = 0 -> VALID conv ; off = -1 -> conv_transpose (k=2,s=1,VALID,
// transpose_kernel=False semantics).
// EPI: 0 = +bias only ; 1 = relu(g*((acc+bias)*bns)+bt)
// ============================================================
template<int EPI>
__global__ __launch_bounds__(256)
void conv_gemm(const float* __restrict__ in, const float* __restrict__ wts,
               const float* __restrict__ bias, const float* __restrict__ gamma,
               const float* __restrict__ beta, float* __restrict__ out,
               int IH, int IW, int Cin, int cinShift, int OHOW, int OW,
               int N, int K, int off, float bns)
{
    __shared__ float As[TK][TM];        // [k][m]
    __shared__ float Bs[TK][BSTRIDE];   // [k][n]

    const int tid = threadIdx.x;
    const int tx = tid & 15, ty = tid >> 4;
    const int m0 = blockIdx.x * TM;
    const int n0 = blockIdx.y * TN;

    // ---- A loader: thread loads 16 floats of row ra at k-offset kh ----
    const int ra = tid >> 1;
    const int kh = (tid & 1) << 4;
    const float* tap[4];
    bool tv[4];
    {
        int m = m0 + ra;
        int b = m / OHOW;
        int rem = m - b * OHOW;
        int oi = rem / OW;
        int oj = rem - oi * OW;
#pragma unroll
        for (int t = 0; t < 4; ++t) {
            int ii = oi + (t >> 1) + off;
            int jj = oj + (t & 1) + off;
            bool v = (ii >= 0) && (ii < IH) && (jj >= 0) && (jj < IW);
            tv[t] = v;
            tap[t] = in + (((long)b * IH + (v ? ii : 0)) * IW + (v ? jj : 0)) * Cin;
        }
    }

    // ---- B loader: row rb of chunk, 16 cols at cbcol ----
    const int rb = tid >> 3;
    const int cbcol = (tid & 7) << 4;
    const float* bptr = wts + (long)rb * N + n0 + cbcol;

    f4 acc[2][2][4];
#pragma unroll
    for (int a_ = 0; a_ < 2; ++a_)
#pragma unroll
        for (int b_ = 0; b_ < 2; ++b_)
#pragma unroll
            for (int i = 0; i < 4; ++i)
                acc[a_][b_][i] = (f4){0.f, 0.f, 0.f, 0.f};

    const int cmask = Cin - 1;

    for (int kc = 0; kc < K; kc += TK) {
        // global loads (Cin is a multiple of 32, so the 16-float run stays in one tap)
        int kk = kc + kh;
        int t = kk >> cinShift;
        int ci = kk & cmask;
        f4 av[4];
#pragma unroll
        for (int q = 0; q < 4; ++q) av[q] = (f4){0.f, 0.f, 0.f, 0.f};
        if (tv[t]) {
            const float* p = tap[t] + ci;
#pragma unroll
            for (int q = 0; q < 4; ++q) av[q] = ldg4(p + 4 * q);
        }
        const float* bp = bptr + (long)kc * N;
        f4 bv[4];
#pragma unroll
        for (int q = 0; q < 4; ++q) bv[q] = ldg4(bp + 4 * q);

        __syncthreads();
#pragma unroll
        for (int q = 0; q < 4; ++q) {
#pragma unroll
            for (int e = 0; e < 4; ++e) As[kh + 4 * q + e][ra] = av[q][e];
        }
#pragma unroll
        for (int q = 0; q < 4; ++q)
            *(f4*)&Bs[rb][cbcol + 4 * q] = bv[q];
        __syncthreads();

        const f4* A4 = (const f4*)(&As[0][0]);
        const f4* B4 = (const f4*)(&Bs[0][0]);
#pragma unroll 8
        for (int k = 0; k < TK; ++k) {
            f4 a0 = A4[k * (TM / 4) + ty];
            f4 a1 = A4[k * (TM / 4) + 16 + ty];
            f4 b0 = B4[k * (BSTRIDE / 4) + tx];
            f4 b1 = B4[k * (BSTRIDE / 4) + 16 + tx];
#pragma unroll
            for (int i = 0; i < 4; ++i) {
                acc[0][0][i] += b0 * a0[i];
                acc[0][1][i] += b1 * a0[i];
                acc[1][0][i] += b0 * a1[i];
                acc[1][1][i] += b1 * a1[i];
            }
        }
    }

    // ---- epilogue ----
    f4 bia[2], gam[2], bet[2];
#pragma unroll
    for (int c_ = 0; c_ < 2; ++c_) {
        int c = n0 + c_ * 64 + tx * 4;
        bia[c_] = ldg4(bias + c);
        if (EPI == 1) { gam[c_] = ldg4(gamma + c); bet[c_] = ldg4(beta + c); }
    }
#pragma unroll
    for (int r_ = 0; r_ < 2; ++r_) {
#pragma unroll
        for (int i = 0; i < 4; ++i) {
            long row = m0 + r_ * 64 + ty * 4 + i;
            float* orow = out + row * (long)N + n0;
#pragma unroll
            for (int c_ = 0; c_ < 2; ++c_) {
                f4 v = acc[r_][c_][i] + bia[c_];
                if (EPI == 1) {
                    v = gam[c_] * (v * bns) + bet[c_];
#pragma unroll
                    for (int e = 0; e < 4; ++e) v[e] = fmaxf(v[e], 0.f);
                }
                *(f4*)&orow[c_ * 64 + tx * 4] = v;
            }
        }
    }
}

// ============================================================
// VQ: dist[m,n] = (fn[m] + cn[n]) - 2 * <xe[m], cb[n]>, argmin_n fused.
// Block covers 128 rows x all 128 codes.
// ============================================================
__global__ __launch_bounds__(256)
void vq_gemm_argmin(const float* __restrict__ xe, const float* __restrict__ cb,
                    const float* __restrict__ fn, const float* __restrict__ cn,
                    int* __restrict__ idxo)
{
    __shared__ float As[TK][TM];
    __shared__ float Bs[TK][BSTRIDE];
    const int tid = threadIdx.x;
    const int tx = tid & 15, ty = tid >> 4;
    const int m0 = blockIdx.x * TM;
    const int ra = tid >> 1;
    const int kh = (tid & 1) << 4;
    const float* aptr = xe + (long)(m0 + ra) * 1024 + kh;
    const float* bptr = cb + (long)ra * 1024 + kh;   // ra doubles as code row 0..127

    f4 acc[2][2][4];
#pragma unroll
    for (int a_ = 0; a_ < 2; ++a_)
#pragma unroll
        for (int b_ = 0; b_ < 2; ++b_)
#pragma unroll
            for (int i = 0; i < 4; ++i)
                acc[a_][b_][i] = (f4){0.f, 0.f, 0.f, 0.f};

    for (int kc = 0; kc < 1024; kc += TK) {
        f4 av[4], bv[4];
#pragma unroll
        for (int q = 0; q < 4; ++q) {
            av[q] = ldg4(aptr + kc + 4 * q);
            bv[q] = ldg4(bptr + kc + 4 * q);
        }
        __syncthreads();
#pragma unroll
        for (int q = 0; q < 4; ++q) {
#pragma unroll
            for (int e = 0; e < 4; ++e) {
                As[kh + 4 * q + e][ra] = av[q][e];
                Bs[kh + 4 * q + e][ra] = bv[q][e];
            }
        }
        __syncthreads();

        const f4* A4 = (const f4*)(&As[0][0]);
        const f4* B4 = (const f4*)(&Bs[0][0]);
#pragma unroll 8
        for (int k = 0; k < TK; ++k) {
            f4 a0 = A4[k * (TM / 4) + ty];
            f4 a1 = A4[k * (TM / 4) + 16 + ty];
            f4 b0 = B4[k * (BSTRIDE / 4) + tx];
            f4 b1 = B4[k * (BSTRIDE / 4) + 16 + tx];
#pragma unroll
            for (int i = 0; i < 4; ++i) {
                acc[0][0][i] += b0 * a0[i];
                acc[0][1][i] += b1 * a0[i];
                acc[1][0][i] += b0 * a1[i];
                acc[1][1][i] += b1 * a1[i];
            }
        }
    }

    // codes handled by this thread
    float cnv[2][4];
#pragma unroll
    for (int c_ = 0; c_ < 2; ++c_)
#pragma unroll
        for (int j = 0; j < 4; ++j)
            cnv[c_][j] = cn[c_ * 64 + tx * 4 + j];

#pragma unroll
    for (int r_ = 0; r_ < 2; ++r_) {
#pragma unroll
        for (int i = 0; i < 4; ++i) {
            int m = m0 + r_ * 64 + ty * 4 + i;
            float f = fn[m];
            float best = 3.4e38f;
            int bi = 0;
#pragma unroll
            for (int c_ = 0; c_ < 2; ++c_) {
#pragma unroll
                for (int j = 0; j < 4; ++j) {
                    int col = c_ * 64 + tx * 4 + j;
                    float d = (f + cnv[c_][j]) - 2.0f * acc[r_][c_][i][j];
                    if (d < best) { best = d; bi = col; }   // first-min tie rule
                }
            }
#pragma unroll
            for (int sh = 1; sh <= 8; sh <<= 1) {
                float ov = __shfl_xor(best, sh, 64);
                int ob = __shfl_xor(bi, sh, 64);
                if (ov < best || (ov == best && ob < bi)) { best = ov; bi = ob; }
            }
            if (tx == 0) idxo[m] = bi;
        }
    }
}

// one wave per row: sum of squares
__global__ void rownorm(const float* __restrict__ x, float* __restrict__ o, int rows)
{
    int w = blockIdx.x * (blockDim.x >> 6) + (threadIdx.x >> 6);
    int lane = threadIdx.x & 63;
    if (w >= rows) return;
    const f4* p = (const f4*)(x + (long)w * 1024);
    f4 s = (f4){0.f, 0.f, 0.f, 0.f};
#pragma unroll
    for (int it = 0; it < 4; ++it) {
        f4 v = p[it * 64 + lane];
        s += v * v;
    }
    float t = (s[0] + s[1]) + (s[2] + s[3]);
#pragma unroll
    for (int sh = 32; sh; sh >>= 1) t += __shfl_xor(t, sh, 64);
    if (lane == 0) o[w] = t;
}

__global__ void gather_rows(const float* __restrict__ cb, const int* __restrict__ idxo,
                            float* __restrict__ q)
{
    int m = blockIdx.x;
    int c = idxo[m];
    const f4* src = (const f4*)(cb + (long)c * 1024);
    f4* dst = (f4*)(q + (long)m * 1024);
    dst[threadIdx.x] = src[threadIdx.x];
}

__global__ void sqdiff_partial(const float* __restrict__ a, const float* __restrict__ b,
                               double* __restrict__ part, long n4)
{
    __shared__ double red[256];
    long i = (long)blockIdx.x * blockDim.x + threadIdx.x;
    long stride = (long)gridDim.x * blockDim.x;
    const f4* A = (const f4*)a;
    const f4* B = (const f4*)b;
    f4 s = (f4){0.f, 0.f, 0.f, 0.f};
    for (; i < n4; i += stride) {
        f4 d = A[i] - B[i];
        s += d * d;
    }
    double t = ((double)s[0] + s[1]) + ((double)s[2] + s[3]);
    red[threadIdx.x] = t;
    __syncthreads();
    for (int h = 128; h; h >>= 1) {
        if (threadIdx.x < h) red[threadIdx.x] += red[threadIdx.x + h];
        __syncthreads();
    }
    if (threadIdx.x == 0) part[blockIdx.x] = red[0];
}

__global__ void finalize_k(const double* __restrict__ pa, int na,
                           const double* __restrict__ pb, int nb,
                           float* __restrict__ loss)
{
    __shared__ double red[256];
    int t = threadIdx.x;
    double sa = 0;
    for (int i = t; i < na; i += 256) sa += pa[i];
    red[t] = sa; __syncthreads();
    for (int h = 128; h; h >>= 1) { if (t < h) red[t] += red[t + h]; __syncthreads(); }
    double SA = red[0];
    __syncthreads();
    double sb = 0;
    for (int i = t; i < nb; i += 256) sb += pb[i];
    red[t] = sb; __syncthreads();
    for (int h = 128; h; h >>= 1) { if (t < h) red[t] += red[t + h]; __syncthreads(); }
    if (t == 0) {
        double recon = SA / 8388608.0;
        double vql = red[0] / 44302336.0;
        loss[0] = (float)(recon + 1.25 * vql);   // recon + vq_l + 0.25*commit, vq_l==commit
    }
}

__global__ void vq_mean_k(const float* __restrict__ vqx, const float* __restrict__ mask,
                          float* __restrict__ o)
{
    __shared__ float red[128];
    int b = blockIdx.x;
    int d = threadIdx.x;   // 128 threads
    red[d] = mask[b * 256 + d] + mask[b * 256 + 128 + d];
    __syncthreads();
    for (int h = 64; h; h >>= 1) { if (d < h) red[d] += red[d + h]; __syncthreads(); }
    float msum = red[0];
    const float* p = vqx + (long)b * 256 * 128 + d;
    float s = 0.f;
    for (int l = 0; l < 256; ++l) s += p[l * 128];
    o[b * 128 + d] = s / msum;
}

extern "C" void kernel_launch(void* const* d_in, const int* in_sizes, int n_in,
                              void* d_out, int out_size, void* d_ws, size_t ws_size,
                              hipStream_t stream)
{
    const float* x    = (const float*)d_in[0];
    const float* mask = (const float*)d_in[1];
    const float* cb   = (const float*)d_in[2];
    const float* ew1 = (const float*)d_in[3];
    const float* eb1 = (const float*)d_in[4];
    const float* eg1 = (const float*)d_in[5];
    const float* ebt1= (const float*)d_in[6];
    const float* ew2 = (const float*)d_in[7];
    const float* eb2 = (const float*)d_in[8];
    const float* eg2 = (const float*)d_in[9];
    const float* ebt2= (const float*)d_in[10];
    const float* ew3 = (const float*)d_in[11];
    const float* eb3 = (const float*)d_in[12];
    const float* dw1 = (const float*)d_in[13];
    const float* db1 = (const float*)d_in[14];
    const float* dg1 = (const float*)d_in[15];
    const float* dbt1= (const float*)d_in[16];
    const float* dw2 = (const float*)d_in[17];
    const float* db2 = (const float*)d_in[18];
    const float* dg2 = (const float*)d_in[19];
    const float* dbt2= (const float*)d_in[20];
    const float* dw3 = (const float*)d_in[21];
    const float* db3 = (const float*)d_in[22];

    float* out = (float*)d_out;
    float* o_vqmean = out;                 // 32768
    float* o_vqx    = out + 32768;         // 8388608
    float* o_xe     = out + 8421376;       // 44302336
    float* o_q      = out + 52723712;      // 44302336
    float* o_loss   = out + 97026048;      // 1

    float* base;
    if (ws_size >= (size_t)WS_FLOATS * 4) {
        base = (float*)d_ws;
    } else {
        void* p = nullptr;
        hipGetSymbolAddress(&p, HIP_SYMBOL(g_fallback));
        base = (float*)p;
    }
    float* h1 = base;            // also d2
    float* h2 = h1 + H1_F;       // also d1
    float* fn = h2 + H2_F;
    float* cn = fn + 43264;
    int*  idxb = (int*)(cn + 128);
    double* pa = (double*)(idxb + 43264);
    double* pb = pa + 2048;

    const float bns = (float)(1.0 / sqrt(1.0 + 1e-3));

    // ---- encoder ----
    conv_gemm<1><<<dim3(450, 2), 256, 0, stream>>>(x,  ew1, eb1, eg1, ebt1, h1,
        16, 16, 128, 7, 225, 15, 256, 512, 0, bns);
    conv_gemm<1><<<dim3(392, 4), 256, 0, stream>>>(h1, ew2, eb2, eg2, ebt2, h2,
        15, 15, 256, 8, 196, 14, 512, 1024, 0, bns);
    conv_gemm<0><<<dim3(338, 8), 256, 0, stream>>>(h2, ew3, eb3, nullptr, nullptr, o_xe,
        14, 14, 512, 9, 169, 13, 1024, 2048, 0, bns);

    // ---- VQ ----
    rownorm<<<10816, 256, 0, stream>>>(o_xe, fn, 43264);
    rownorm<<<32, 256, 0, stream>>>(cb, cn, 128);
    vq_gemm_argmin<<<338, 256, 0, stream>>>(o_xe, cb, fn, cn, idxb);
    gather_rows<<<43264, 256, 0, stream>>>(cb, idxb, o_q);

    // ---- decoder (ste forward value == quantized) ----
    conv_gemm<1><<<dim3(392, 4), 256, 0, stream>>>(o_q, dw1, db1, dg1, dbt1, h2,
        13, 13, 1024, 10, 196, 14, 512, 4096, -1, bns);
    conv_gemm<1><<<dim3(450, 2), 256, 0, stream>>>(h2, dw2, db2, dg2, dbt2, h1,
        14, 14, 512, 9, 225, 15, 256, 2048, -1, bns);
    conv_gemm<0><<<dim3(512, 1), 256, 0, stream>>>(h1, dw3, db3, nullptr, nullptr, o_vqx,
        15, 15, 256, 8, 256, 16, 128, 1024, -1, bns);

    // ---- outputs ----
    vq_mean_k<<<256, 128, 0, stream>>>(o_vqx, mask, o_vqmean);
    sqdiff_partial<<<1024, 256, 0, stream>>>(x, o_vqx, pa, 2097152L);
    sqdiff_partial<<<2048, 256, 0, stream>>>(o_q, o_xe, pb, 11075584L);
    finalize_k<<<1, 256, 0, stream>>>(pa, 1024, pb, 2048, o_loss);
}

// Round 2
// 1578.308 us; speedup vs baseline: 4.1821x; 4.1821x over previous
//
#include <hip/hip_runtime.h>
#include <math.h>

typedef float f4 __attribute__((ext_vector_type(4)));
typedef short s8 __attribute__((ext_vector_type(8)));

// ---------------- workspace layout (floats) ----------------
#define WS_FLOATS 64942720L
__device__ float g_fallback[WS_FLOATS];

__device__ __forceinline__ f4 ldg4(const float* p) { return *(const f4*)p; }

__device__ __forceinline__ unsigned short bfr(float x) {   // fp32 -> bf16 RNE
    unsigned int u = __float_as_uint(x);
    u += 0x7fffu + ((u >> 16) & 1u);
    return (unsigned short)(u >> 16);
}
__device__ __forceinline__ float bff(unsigned short h) {
    return __uint_as_float(((unsigned int)h) << 16);
}
__device__ __forceinline__ s8 z8() { s8 z = {0,0,0,0,0,0,0,0}; return z; }

__device__ __forceinline__ void split8(const f4& x0, const f4& x1, s8& hi, s8& lo) {
#pragma unroll
    for (int e = 0; e < 4; ++e) {
        unsigned short h0 = bfr(x0[e]);
        hi[e] = (short)h0; lo[e] = (short)bfr(x0[e] - bff(h0));
        unsigned short h1 = bfr(x1[e]);
        hi[e + 4] = (short)h1; lo[e + 4] = (short)bfr(x1[e] - bff(h1));
    }
}

// ============================================================
// MFMA implicit-GEMM conv / convT.
// out[b,oi,oj,co] = sum_{t,ci} in[b, oi+(t>>1)+off, oj+(t&1)+off, ci] * W[t*Cin+ci][co]
// Weights pre-transposed to [N][K] bf16 (hi [,lo]).
// SPLIT: 1 = plain bf16 ; 2 = bf16x2 split (3 MFMAs, fp32-grade)
// ASRC : 0 = fp32 (convert+split on the fly)
//        1 = bf16 plane pair (hi,lo)
//        2 = bf16 single plane
//        3 = gather-quantized: aHi = cb_bf [128][Cin], gidx = row->code
// EPI  : 0 = +bias ; 1 = relu(g*((acc+bias)*bns)+bt)
// OUTF : 0 = fp32 ; 1 = bf16 plane pair ; 2 = bf16 single
// ============================================================
template<int SPLIT, int ASRC, int EPI, int OUTF>
__global__ __launch_bounds__(256, 2)
void mfma_conv(const void* __restrict__ aHi, const void* __restrict__ aLo,
               const int* __restrict__ gidx,
               const short* __restrict__ wHi, const short* __restrict__ wLo,
               const float* __restrict__ bias, const float* __restrict__ gamma,
               const float* __restrict__ beta,
               void* __restrict__ oHi, void* __restrict__ oLo,
               int IH, int IW, int Cin, int cinShift, int OHOW, int OW,
               int N, int K, int off, float bns)
{
    constexpr int PL = 128 * 64;           // one LDS plane (shorts)
    __shared__ short smem[2 * SPLIT * PL];
    short* Ah = smem;
    short* Al = smem + PL;                  // SPLIT==2 only
    short* Bh = smem + SPLIT * PL;
    short* Bl = smem + SPLIT * PL + PL;     // SPLIT==2 only

    const int tid = threadIdx.x;
    const int lane = tid & 63, wid = tid >> 6;
    const int fr = lane & 15, fq = lane >> 4;
    const int wm = (wid >> 1) * 64, wn = (wid & 1) * 64;
    const int m0 = blockIdx.x * 128, n0 = blockIdx.y * 128;

    // ---- staging mapping: thread (tid) stages row sr, k-half skh ----
    const int sr = tid >> 1;
    const int skh = (tid & 1) << 5;        // 0 or 32

    long tapOff[4]; bool tv[4];
    {
        int m = m0 + sr;
        int b = m / OHOW; int rem = m - b * OHOW;
        int oi = rem / OW; int oj = rem - oi * OW;
#pragma unroll
        for (int t = 0; t < 4; ++t) {
            int ii = oi + (t >> 1) + off, jj = oj + (t & 1) + off;
            bool v = (ii >= 0) && (ii < IH) && (jj >= 0) && (jj < IW);
            tv[t] = v;
            tapOff[t] = ((long)b * IH + (v ? ii : 0)) * IW + (v ? jj : 0);
        }
    }
    int code[4];
    if (ASRC == 3) {
#pragma unroll
        for (int t = 0; t < 4; ++t) code[t] = tv[t] ? gidx[tapOff[t]] : 0;
    }

    f4 acc[4][4];
#pragma unroll
    for (int a = 0; a < 4; ++a)
#pragma unroll
        for (int b = 0; b < 4; ++b) acc[a][b] = (f4){0.f, 0.f, 0.f, 0.f};

    const short* wHrow = wHi + (long)(n0 + sr) * K;
    const short* wLrow = (SPLIT == 2) ? (wLo + (long)(n0 + sr) * K) : nullptr;

    const int swzW = (sr & 7) << 3;
    const int sbase = sr * 64;

    for (int kc = 0; kc < K; kc += 64) {
        const int kk = kc + skh;
        const int t = kk >> cinShift;
        const int ci = kk & (Cin - 1);
        const bool v = tv[t];

        s8 ah[4], al[4], bh[4], bl[4];
        if (ASRC == 0) {
            const float* p = (const float*)aHi + tapOff[t] * Cin + ci;
#pragma unroll
            for (int q = 0; q < 4; ++q) {
                f4 x0 = v ? ldg4(p + 8 * q) : (f4){0.f,0.f,0.f,0.f};
                f4 x1 = v ? ldg4(p + 8 * q + 4) : (f4){0.f,0.f,0.f,0.f};
                split8(x0, x1, ah[q], al[q]);
            }
        } else if (ASRC == 1) {
            const short* ph = (const short*)aHi + tapOff[t] * Cin + ci;
            const short* pl = (const short*)aLo + tapOff[t] * Cin + ci;
#pragma unroll
            for (int q = 0; q < 4; ++q) {
                ah[q] = v ? *(const s8*)(ph + 8 * q) : z8();
                al[q] = v ? *(const s8*)(pl + 8 * q) : z8();
            }
        } else if (ASRC == 2) {
            const short* ph = (const short*)aHi + tapOff[t] * Cin + ci;
#pragma unroll
            for (int q = 0; q < 4; ++q) ah[q] = v ? *(const s8*)(ph + 8 * q) : z8();
        } else {
            const short* ph = (const short*)aHi + (long)code[t] * Cin + ci;
#pragma unroll
            for (int q = 0; q < 4; ++q) ah[q] = v ? *(const s8*)(ph + 8 * q) : z8();
        }
#pragma unroll
        for (int q = 0; q < 4; ++q) {
            bh[q] = *(const s8*)(wHrow + kc + skh + 8 * q);
            if (SPLIT == 2) bl[q] = *(const s8*)(wLrow + kc + skh + 8 * q);
        }

        __syncthreads();
#pragma unroll
        for (int q = 0; q < 4; ++q) {
            int kx = (skh + 8 * q) ^ swzW;
            *(s8*)&Ah[sbase + kx] = ah[q];
            if (SPLIT == 2) *(s8*)&Al[sbase + kx] = al[q];
            *(s8*)&Bh[sbase + kx] = bh[q];
            if (SPLIT == 2) *(s8*)&Bl[sbase + kx] = bl[q];
        }
        __syncthreads();

#pragma unroll
        for (int ks = 0; ks < 2; ++ks) {
            const int colk = ks * 32 + fq * 8;
            s8 afh[4], afl[4], bfh[4], bfl[4];
#pragma unroll
            for (int mf = 0; mf < 4; ++mf) {
                int ar = wm + mf * 16 + fr;
                int ai = ar * 64 + (colk ^ ((ar & 7) << 3));
                afh[mf] = *(const s8*)&Ah[ai];
                if (SPLIT == 2) afl[mf] = *(const s8*)&Al[ai];
            }
#pragma unroll
            for (int nf = 0; nf < 4; ++nf) {
                int br = wn + nf * 16 + fr;
                int bi2 = br * 64 + (colk ^ ((br & 7) << 3));
                bfh[nf] = *(const s8*)&Bh[bi2];
                if (SPLIT == 2) bfl[nf] = *(const s8*)&Bl[bi2];
            }
#pragma unroll
            for (int mf = 0; mf < 4; ++mf)
#pragma unroll
                for (int nf = 0; nf < 4; ++nf) {
                    acc[mf][nf] = __builtin_amdgcn_mfma_f32_16x16x32_bf16(
                        afh[mf], bfh[nf], acc[mf][nf], 0, 0, 0);
                    if (SPLIT == 2) {
                        acc[mf][nf] = __builtin_amdgcn_mfma_f32_16x16x32_bf16(
                            afh[mf], bfl[nf], acc[mf][nf], 0, 0, 0);
                        acc[mf][nf] = __builtin_amdgcn_mfma_f32_16x16x32_bf16(
                            afl[mf], bfh[nf], acc[mf][nf], 0, 0, 0);
                    }
                }
        }
    }

    // ---- epilogue ----
    float bi[4], ga[4], be[4];
#pragma unroll
    for (int nf = 0; nf < 4; ++nf) {
        int col = n0 + wn + nf * 16 + fr;
        bi[nf] = bias[col];
        if (EPI == 1) { ga[nf] = gamma[col]; be[nf] = beta[col]; }
    }
#pragma unroll
    for (int mf = 0; mf < 4; ++mf)
#pragma unroll
        for (int j = 0; j < 4; ++j) {
            long gm = m0 + wm + mf * 16 + fq * 4 + j;
#pragma unroll
            for (int nf = 0; nf < 4; ++nf) {
                int col = n0 + wn + nf * 16 + fr;
                float vv = acc[mf][nf][j] + bi[nf];
                if (EPI == 1) {
                    vv = ga[nf] * (vv * bns) + be[nf];
                    vv = fmaxf(vv, 0.f);
                }
                long o = gm * (long)N + col;
                if (OUTF == 0) {
                    ((float*)oHi)[o] = vv;
                } else if (OUTF == 2) {
                    ((short*)oHi)[o] = (short)bfr(vv);
                } else {
                    unsigned short h = bfr(vv);
                    ((short*)oHi)[o] = (short)h;
                    ((short*)oLo)[o] = (short)bfr(vv - bff(h));
                }
            }
        }
}

// ---- weight prep: [K][N] fp32 -> [N][K] bf16 hi (,lo) ----
__global__ void wprep(const float* __restrict__ w, short* __restrict__ hi,
                      short* __restrict__ lo, int kshift, int total, int N)
{
    int i = blockIdx.x * 256 + threadIdx.x;
    if (i >= total) return;
    int K = 1 << kshift;
    int n = i >> kshift, k = i & (K - 1);
    float x = w[(long)k * N + n];
    unsigned short h = bfr(x);
    hi[i] = (short)h;
    if (lo) lo[i] = (short)bfr(x - bff(h));
}

__global__ void cbprep(const float* __restrict__ cb, short* __restrict__ o)
{
    int i = blockIdx.x * 256 + threadIdx.x;
    o[i] = (short)bfr(cb[i]);
}

// ============================================================
// VQ: dist[m,n] = (fn[m] + cn[n]) - 2 * <xe[m], cb[n]>, fused argmin (fp32)
// ============================================================
#define TM 128
#define TK 32
#define BSTRIDE (128 + 4)

__global__ __launch_bounds__(256)
void vq_gemm_argmin(const float* __restrict__ xe, const float* __restrict__ cb,
                    const float* __restrict__ fn, const float* __restrict__ cn,
                    int* __restrict__ idxo)
{
    __shared__ float As[TK][TM];
    __shared__ float Bs[TK][BSTRIDE];
    const int tid = threadIdx.x;
    const int tx = tid & 15, ty = tid >> 4;
    const int m0 = blockIdx.x * TM;
    const int ra = tid >> 1;
    const int kh = (tid & 1) << 4;
    const float* aptr = xe + (long)(m0 + ra) * 1024 + kh;
    const float* bptr = cb + (long)ra * 1024 + kh;

    f4 acc[2][2][4];
#pragma unroll
    for (int a_ = 0; a_ < 2; ++a_)
#pragma unroll
        for (int b_ = 0; b_ < 2; ++b_)
#pragma unroll
            for (int i = 0; i < 4; ++i)
                acc[a_][b_][i] = (f4){0.f, 0.f, 0.f, 0.f};

    for (int kc = 0; kc < 1024; kc += TK) {
        f4 av[4], bv[4];
#pragma unroll
        for (int q = 0; q < 4; ++q) {
            av[q] = ldg4(aptr + kc + 4 * q);
            bv[q] = ldg4(bptr + kc + 4 * q);
        }
        __syncthreads();
#pragma unroll
        for (int q = 0; q < 4; ++q) {
#pragma unroll
            for (int e = 0; e < 4; ++e) {
                As[kh + 4 * q + e][ra] = av[q][e];
                Bs[kh + 4 * q + e][ra] = bv[q][e];
            }
        }
        __syncthreads();

        const f4* A4 = (const f4*)(&As[0][0]);
        const f4* B4 = (const f4*)(&Bs[0][0]);
#pragma unroll 8
        for (int k = 0; k < TK; ++k) {
            f4 a0 = A4[k * (TM / 4) + ty];
            f4 a1 = A4[k * (TM / 4) + 16 + ty];
            f4 b0 = B4[k * (BSTRIDE / 4) + tx];
            f4 b1 = B4[k * (BSTRIDE / 4) + 16 + tx];
#pragma unroll
            for (int i = 0; i < 4; ++i) {
                acc[0][0][i] += b0 * a0[i];
                acc[0][1][i] += b1 * a0[i];
                acc[1][0][i] += b0 * a1[i];
                acc[1][1][i] += b1 * a1[i];
            }
        }
    }

    float cnv[2][4];
#pragma unroll
    for (int c_ = 0; c_ < 2; ++c_)
#pragma unroll
        for (int j = 0; j < 4; ++j)
            cnv[c_][j] = cn[c_ * 64 + tx * 4 + j];

#pragma unroll
    for (int r_ = 0; r_ < 2; ++r_) {
#pragma unroll
        for (int i = 0; i < 4; ++i) {
            int m = m0 + r_ * 64 + ty * 4 + i;
            float f = fn[m];
            float best = 3.4e38f;
            int bi = 0;
#pragma unroll
            for (int c_ = 0; c_ < 2; ++c_) {
#pragma unroll
                for (int j = 0; j < 4; ++j) {
                    int col = c_ * 64 + tx * 4 + j;
                    float d = (f + cnv[c_][j]) - 2.0f * acc[r_][c_][i][j];
                    if (d < best) { best = d; bi = col; }
                }
            }
#pragma unroll
            for (int sh = 1; sh <= 8; sh <<= 1) {
                float ov = __shfl_xor(best, sh, 64);
                int ob = __shfl_xor(bi, sh, 64);
                if (ov < best || (ov == best && ob < bi)) { best = ov; bi = ob; }
            }
            if (tx == 0) idxo[m] = bi;
        }
    }
}

__global__ void rownorm(const float* __restrict__ x, float* __restrict__ o, int rows)
{
    int w = blockIdx.x * (blockDim.x >> 6) + (threadIdx.x >> 6);
    int lane = threadIdx.x & 63;
    if (w >= rows) return;
    const f4* p = (const f4*)(x + (long)w * 1024);
    f4 s = (f4){0.f, 0.f, 0.f, 0.f};
#pragma unroll
    for (int it = 0; it < 4; ++it) {
        f4 v = p[it * 64 + lane];
        s += v * v;
    }
    float t = (s[0] + s[1]) + (s[2] + s[3]);
#pragma unroll
    for (int sh = 32; sh; sh >>= 1) t += __shfl_xor(t, sh, 64);
    if (lane == 0) o[w] = t;
}

__global__ void gather_rows(const float* __restrict__ cb, const int* __restrict__ idxo,
                            float* __restrict__ q)
{
    int m = blockIdx.x;
    int c = idxo[m];
    const f4* src = (const f4*)(cb + (long)c * 1024);
    f4* dst = (f4*)(q + (long)m * 1024);
    dst[threadIdx.x] = src[threadIdx.x];
}

__global__ void sqdiff_partial(const float* __restrict__ a, const float* __restrict__ b,
                               double* __restrict__ part, long n4)
{
    __shared__ double red[256];
    long i = (long)blockIdx.x * blockDim.x + threadIdx.x;
    long stride = (long)gridDim.x * blockDim.x;
    const f4* A = (const f4*)a;
    const f4* B = (const f4*)b;
    f4 s = (f4){0.f, 0.f, 0.f, 0.f};
    for (; i < n4; i += stride) {
        f4 d = A[i] - B[i];
        s += d * d;
    }
    double t = ((double)s[0] + s[1]) + ((double)s[2] + s[3]);
    red[threadIdx.x] = t;
    __syncthreads();
    for (int h = 128; h; h >>= 1) {
        if (threadIdx.x < h) red[threadIdx.x] += red[threadIdx.x + h];
        __syncthreads();
    }
    if (threadIdx.x == 0) part[blockIdx.x] = red[0];
}

__global__ void finalize_k(const double* __restrict__ pa, int na,
                           const double* __restrict__ pb, int nb,
                           float* __restrict__ loss)
{
    __shared__ double red[256];
    int t = threadIdx.x;
    double sa = 0;
    for (int i = t; i < na; i += 256) sa += pa[i];
    red[t] = sa; __syncthreads();
    for (int h = 128; h; h >>= 1) { if (t < h) red[t] += red[t + h]; __syncthreads(); }
    double SA = red[0];
    __syncthreads();
    double sb = 0;
    for (int i = t; i < nb; i += 256) sb += pb[i];
    red[t] = sb; __syncthreads();
    for (int h = 128; h; h >>= 1) { if (t < h) red[t] += red[t + h]; __syncthreads(); }
    if (t == 0) {
        double recon = SA / 8388608.0;
        double vql = red[0] / 44302336.0;
        loss[0] = (float)(recon + 1.25 * vql);
    }
}

__global__ void vq_mean_k(const float* __restrict__ vqx, const float* __restrict__ mask,
                          float* __restrict__ o)
{
    __shared__ float red[128];
    int b = blockIdx.x;
    int d = threadIdx.x;
    red[d] = mask[b * 256 + d] + mask[b * 256 + 128 + d];
    __syncthreads();
    for (int h = 64; h; h >>= 1) { if (d < h) red[d] += red[d + h]; __syncthreads(); }
    float msum = red[0];
    const float* p = vqx + (long)b * 256 * 128 + d;
    float s = 0.f;
    for (int l = 0; l < 256; ++l) s += p[l * 128];
    o[b * 128 + d] = s / msum;
}

extern "C" void kernel_launch(void* const* d_in, const int* in_sizes, int n_in,
                              void* d_out, int out_size, void* d_ws, size_t ws_size,
                              hipStream_t stream)
{
    const float* x    = (const float*)d_in[0];
    const float* mask = (const float*)d_in[1];
    const float* cb   = (const float*)d_in[2];
    const float* ew1 = (const float*)d_in[3];
    const float* eb1 = (const float*)d_in[4];
    const float* eg1 = (const float*)d_in[5];
    const float* ebt1= (const float*)d_in[6];
    const float* ew2 = (const float*)d_in[7];
    const float* eb2 = (const float*)d_in[8];
    const float* eg2 = (const float*)d_in[9];
    const float* ebt2= (const float*)d_in[10];
    const float* ew3 = (const float*)d_in[11];
    const float* eb3 = (const float*)d_in[12];
    const float* dw1 = (const float*)d_in[13];
    const float* db1 = (const float*)d_in[14];
    const float* dg1 = (const float*)d_in[15];
    const float* dbt1= (const float*)d_in[16];
    const float* dw2 = (const float*)d_in[17];
    const float* db2 = (const float*)d_in[18];
    const float* dg2 = (const float*)d_in[19];
    const float* dbt2= (const float*)d_in[20];
    const float* dw3 = (const float*)d_in[21];
    const float* db3 = (const float*)d_in[22];

    float* out = (float*)d_out;
    float* o_vqmean = out;                 // 32768
    float* o_vqx    = out + 32768;         // 8388608
    float* o_xe     = out + 8421376;       // 44302336
    float* o_q      = out + 52723712;      // 44302336
    float* o_loss   = out + 97026048;      // 1

    float* base;
    if (ws_size >= (size_t)WS_FLOATS * 4) {
        base = (float*)d_ws;
    } else {
        void* p = nullptr;
        hipGetSymbolAddress(&p, HIP_SYMBOL(g_fallback));
        base = (float*)p;
    }

    float* cur = base;
    short* h1h = (short*)cur; cur += 7372800;
    short* h1l = (short*)cur; cur += 7372800;
    short* h2h = (short*)cur; cur += 12845056;
    short* h2l = (short*)cur; cur += 12845056;
    short* d1o = (short*)cur; cur += 12845056;
    short* d2o = (short*)cur; cur += 7372800;
    short* ewt1h = (short*)cur; cur += 65536;
    short* ewt1l = (short*)cur; cur += 65536;
    short* ewt2h = (short*)cur; cur += 262144;
    short* ewt2l = (short*)cur; cur += 262144;
    short* ewt3h = (short*)cur; cur += 1048576;
    short* ewt3l = (short*)cur; cur += 1048576;
    short* dwt1h = (short*)cur; cur += 1048576;
    short* dwt2h = (short*)cur; cur += 262144;
    short* dwt3h = (short*)cur; cur += 65536;
    short* cbbf  = (short*)cur; cur += 65536;
    float* fn = cur; cur += 43264;
    float* cn = cur; cur += 128;
    int* idxb = (int*)cur; cur += 43264;
    double* pa = (double*)cur; cur += 4096;
    double* pb = (double*)cur; cur += 4096;

    const float bns = (float)(1.0 / sqrt(1.0 + 1e-3));

    // ---- weight prep (each call; deterministic) ----
    wprep<<<512, 256, 0, stream>>>(ew1, ewt1h, ewt1l, 9, 131072, 256);
    wprep<<<2048, 256, 0, stream>>>(ew2, ewt2h, ewt2l, 10, 524288, 512);
    wprep<<<8192, 256, 0, stream>>>(ew3, ewt3h, ewt3l, 11, 2097152, 1024);
    wprep<<<8192, 256, 0, stream>>>(dw1, dwt1h, nullptr, 12, 2097152, 512);
    wprep<<<2048, 256, 0, stream>>>(dw2, dwt2h, nullptr, 11, 524288, 256);
    wprep<<<512, 256, 0, stream>>>(dw3, dwt3h, nullptr, 10, 131072, 128);
    cbprep<<<512, 256, 0, stream>>>(cb, cbbf);

    // ---- encoder (bf16x2 split, fp32-grade) ----
    mfma_conv<2, 0, 1, 1><<<dim3(450, 2), 256, 0, stream>>>(
        x, nullptr, nullptr, ewt1h, ewt1l, eb1, eg1, ebt1, h1h, h1l,
        16, 16, 128, 7, 225, 15, 256, 512, 0, bns);
    mfma_conv<2, 1, 1, 1><<<dim3(392, 4), 256, 0, stream>>>(
        h1h, h1l, nullptr, ewt2h, ewt2l, eb2, eg2, ebt2, h2h, h2l,
        15, 15, 256, 8, 196, 14, 512, 1024, 0, bns);
    mfma_conv<2, 1, 0, 0><<<dim3(338, 8), 256, 0, stream>>>(
        h2h, h2l, nullptr, ewt3h, ewt3l, eb3, nullptr, nullptr, o_xe, nullptr,
        14, 14, 512, 9, 169, 13, 1024, 2048, 0, bns);

    // ---- VQ (fp32) ----
    rownorm<<<10816, 256, 0, stream>>>(o_xe, fn, 43264);
    rownorm<<<32, 256, 0, stream>>>(cb, cn, 128);
    vq_gemm_argmin<<<338, 256, 0, stream>>>(o_xe, cb, fn, cn, idxb);
    gather_rows<<<43264, 256, 0, stream>>>(cb, idxb, o_q);

    // ---- decoder (plain bf16 MFMA) ----
    mfma_conv<1, 3, 1, 2><<<dim3(392, 4), 256, 0, stream>>>(
        cbbf, nullptr, idxb, dwt1h, nullptr, db1, dg1, dbt1, d1o, nullptr,
        13, 13, 1024, 10, 196, 14, 512, 4096, -1, bns);
    mfma_conv<1, 2, 1, 2><<<dim3(450, 2), 256, 0, stream>>>(
        d1o, nullptr, nullptr, dwt2h, nullptr, db2, dg2, dbt2, d2o, nullptr,
        14, 14, 512, 9, 225, 15, 256, 2048, -1, bns);
    mfma_conv<1, 2, 0, 0><<<dim3(512, 1), 256, 0, stream>>>(
        d2o, nullptr, nullptr, dwt3h, nullptr, db3, nullptr, nullptr, o_vqx, nullptr,
        15, 15, 256, 8, 256, 16, 128, 1024, -1, bns);

    // ---- outputs ----
    vq_mean_k<<<256, 128, 0, stream>>>(o_vqx, mask, o_vqmean);
    sqdiff_partial<<<1024, 256, 0, stream>>>(x, o_vqx, pa, 2097152L);
    sqdiff_partial<<<2048, 256, 0, stream>>>(o_q, o_xe, pb, 11075584L);
    finalize_k<<<1, 256, 0, stream>>>(pa, 1024, pb, 2048, o_loss);
}

// Round 3
// 1392.670 us; speedup vs baseline: 4.7395x; 1.1333x over previous
//
#include <hip/hip_runtime.h>
#include <math.h>

typedef float f4 __attribute__((ext_vector_type(4)));
typedef short s8 __attribute__((ext_vector_type(8)));

#define WS_FLOATS 64942720L
__device__ float g_fallback[WS_FLOATS];

__device__ __forceinline__ f4 ldg4(const float* p) { return *(const f4*)p; }

__device__ __forceinline__ unsigned short bfr(float x) {   // fp32 -> bf16 RNE
    unsigned int u = __float_as_uint(x);
    u += 0x7fffu + ((u >> 16) & 1u);
    return (unsigned short)(u >> 16);
}
__device__ __forceinline__ float bff(unsigned short h) {
    return __uint_as_float(((unsigned int)h) << 16);
}
__device__ __forceinline__ s8 z8() { s8 z = {0,0,0,0,0,0,0,0}; return z; }

__device__ __forceinline__ void split8(const f4& x0, const f4& x1, s8& hi, s8& lo) {
#pragma unroll
    for (int e = 0; e < 4; ++e) {
        unsigned short h0 = bfr(x0[e]);
        hi[e] = (short)h0; lo[e] = (short)bfr(x0[e] - bff(h0));
        unsigned short h1 = bfr(x1[e]);
        hi[e + 4] = (short)h1; lo[e + 4] = (short)bfr(x1[e] - bff(h1));
    }
}

// ============================================================
// Pipelined MFMA implicit-GEMM conv / convT / VQ-distance.
// SPLIT: 1 = plain bf16 ; 2 = bf16x2 split (3 MFMAs, fp32-grade)
// ASRC : 0 = fp32 (split on the fly) ; 1 = bf16 pair ; 2 = bf16 single
//        3 = gather: aHi = cb_bf [128][Cin], gidx = row->code
// EPI  : 0 = +bias ; 1 = relu(bn(..)) ; 2 = VQ argmin (bias = cn, -> idxo)
// OUTF : 0 = fp32 ; 1 = bf16 pair ; 2 = bf16 single
// ============================================================
template<int SPLIT, int ASRC, int EPI, int OUTF>
__global__ __launch_bounds__(256, 2)
void mfma_conv(const void* __restrict__ aHi, const void* __restrict__ aLo,
               const int* __restrict__ gidx,
               const short* __restrict__ wHi, const short* __restrict__ wLo,
               const float* __restrict__ bias, const float* __restrict__ gamma,
               const float* __restrict__ beta,
               void* __restrict__ oHi, void* __restrict__ oLo,
               int* __restrict__ idxo,
               int IH, int IW, int Cin, int cinShift, int OHOW, int OW,
               int N, int K, int off, float bns)
{
    constexpr int PL = 128 * 64;
    __shared__ short smem[2 * SPLIT * PL];
    short* Ah = smem;
    short* Al = smem + PL;
    short* Bh = smem + SPLIT * PL;
    short* Bl = smem + SPLIT * PL + PL;

    const int tid = threadIdx.x;
    const int lane = tid & 63, wid = tid >> 6;
    const int fr = lane & 15, fq = lane >> 4;
    const int wm = (wid >> 1) * 64, wn = (wid & 1) * 64;
    const int m0 = blockIdx.x * 128, n0 = blockIdx.y * 128;

    const int sr = tid >> 1;
    const int skh = (tid & 1) << 5;

    long tapOff[4]; bool tv[4];
    {
        int m = m0 + sr;
        int b = m / OHOW; int rem = m - b * OHOW;
        int oi = rem / OW; int oj = rem - oi * OW;
#pragma unroll
        for (int t = 0; t < 4; ++t) {
            int ii = oi + (t >> 1) + off, jj = oj + (t & 1) + off;
            bool v = (ii >= 0) && (ii < IH) && (jj >= 0) && (jj < IW);
            tv[t] = v;
            tapOff[t] = ((long)b * IH + (v ? ii : 0)) * IW + (v ? jj : 0);
        }
    }
    int code[4];
    if (ASRC == 3) {
#pragma unroll
        for (int t = 0; t < 4; ++t) code[t] = tv[t] ? gidx[tapOff[t]] : 0;
    }

    f4 acc[4][4];
#pragma unroll
    for (int a = 0; a < 4; ++a)
#pragma unroll
        for (int b = 0; b < 4; ++b) acc[a][b] = (f4){0.f, 0.f, 0.f, 0.f};

    const short* wHrow = wHi + (long)(n0 + sr) * K;
    const short* wLrow = (SPLIT == 2) ? (wLo + (long)(n0 + sr) * K) : nullptr;

    const int swzW = (sr & 7) << 3;
    const int sbase = sr * 64;

    s8 rah[4], ral[4], rbh[4], rbl[4];
    f4 rax0[4], rax1[4];

    auto LOADREGS = [&](int kc) {
        const int kk = kc + skh;
        const int t = kk >> cinShift;
        const int ci = kk & (Cin - 1);
        const bool v = tv[t];
        if (ASRC == 0) {
            const float* p = (const float*)aHi + tapOff[t] * Cin + ci;
#pragma unroll
            for (int q = 0; q < 4; ++q) {
                rax0[q] = v ? ldg4(p + 8 * q) : (f4){0.f,0.f,0.f,0.f};
                rax1[q] = v ? ldg4(p + 8 * q + 4) : (f4){0.f,0.f,0.f,0.f};
            }
        } else if (ASRC == 1) {
            const short* ph = (const short*)aHi + tapOff[t] * Cin + ci;
            const short* pl = (const short*)aLo + tapOff[t] * Cin + ci;
#pragma unroll
            for (int q = 0; q < 4; ++q) {
                rah[q] = v ? *(const s8*)(ph + 8 * q) : z8();
                ral[q] = v ? *(const s8*)(pl + 8 * q) : z8();
            }
        } else if (ASRC == 2) {
            const short* ph = (const short*)aHi + tapOff[t] * Cin + ci;
#pragma unroll
            for (int q = 0; q < 4; ++q) rah[q] = v ? *(const s8*)(ph + 8 * q) : z8();
        } else {
            const short* ph = (const short*)aHi + (long)code[t] * Cin + ci;
#pragma unroll
            for (int q = 0; q < 4; ++q) rah[q] = v ? *(const s8*)(ph + 8 * q) : z8();
        }
#pragma unroll
        for (int q = 0; q < 4; ++q) {
            rbh[q] = *(const s8*)(wHrow + kc + skh + 8 * q);
            if (SPLIT == 2) rbl[q] = *(const s8*)(wLrow + kc + skh + 8 * q);
        }
    };

    auto STORE = [&]() {
        if (ASRC == 0) {
#pragma unroll
            for (int q = 0; q < 4; ++q) split8(rax0[q], rax1[q], rah[q], ral[q]);
        }
#pragma unroll
        for (int q = 0; q < 4; ++q) {
            int kx = (skh + 8 * q) ^ swzW;
            *(s8*)&Ah[sbase + kx] = rah[q];
            if (SPLIT == 2) *(s8*)&Al[sbase + kx] = ral[q];
            *(s8*)&Bh[sbase + kx] = rbh[q];
            if (SPLIT == 2) *(s8*)&Bl[sbase + kx] = rbl[q];
        }
    };

    LOADREGS(0);
    for (int kc = 0; kc < K; kc += 64) {
        __syncthreads();
        STORE();
        __syncthreads();
        if (kc + 64 < K) LOADREGS(kc + 64);

        __builtin_amdgcn_s_setprio(1);
#pragma unroll
        for (int ks = 0; ks < 2; ++ks) {
            const int colk = ks * 32 + fq * 8;
            s8 afh[4], afl[4], bfh[4], bfl[4];
#pragma unroll
            for (int mf = 0; mf < 4; ++mf) {
                int ar = wm + mf * 16 + fr;
                int ai = ar * 64 + (colk ^ ((ar & 7) << 3));
                afh[mf] = *(const s8*)&Ah[ai];
                if (SPLIT == 2) afl[mf] = *(const s8*)&Al[ai];
            }
#pragma unroll
            for (int nf = 0; nf < 4; ++nf) {
                int br = wn + nf * 16 + fr;
                int bi2 = br * 64 + (colk ^ ((br & 7) << 3));
                bfh[nf] = *(const s8*)&Bh[bi2];
                if (SPLIT == 2) bfl[nf] = *(const s8*)&Bl[bi2];
            }
#pragma unroll
            for (int mf = 0; mf < 4; ++mf)
#pragma unroll
                for (int nf = 0; nf < 4; ++nf) {
                    acc[mf][nf] = __builtin_amdgcn_mfma_f32_16x16x32_bf16(
                        afh[mf], bfh[nf], acc[mf][nf], 0, 0, 0);
                    if (SPLIT == 2) {
                        acc[mf][nf] = __builtin_amdgcn_mfma_f32_16x16x32_bf16(
                            afh[mf], bfl[nf], acc[mf][nf], 0, 0, 0);
                        acc[mf][nf] = __builtin_amdgcn_mfma_f32_16x16x32_bf16(
                            afl[mf], bfh[nf], acc[mf][nf], 0, 0, 0);
                    }
                }
        }
        __builtin_amdgcn_s_setprio(0);
    }

    if (EPI == 2) {
        __syncthreads();
        float* pbv = (float*)smem;
        int*   piv = (int*)((float*)smem + 256);
        float cnv[4];
#pragma unroll
        for (int nf = 0; nf < 4; ++nf) cnv[nf] = bias[n0 + wn + nf * 16 + fr];
#pragma unroll
        for (int mf = 0; mf < 4; ++mf)
#pragma unroll
            for (int j = 0; j < 4; ++j) {
                float best = 3.4e38f; int bi = 0;
#pragma unroll
                for (int nf = 0; nf < 4; ++nf) {
                    float d = cnv[nf] - 2.0f * acc[mf][nf][j];
                    int col = wn + nf * 16 + fr;
                    if (d < best) { best = d; bi = col; }
                }
#pragma unroll
                for (int sh = 1; sh <= 8; sh <<= 1) {
                    float ov = __shfl_xor(best, sh, 64);
                    int ob = __shfl_xor(bi, sh, 64);
                    if (ov < best || (ov == best && ob < bi)) { best = ov; bi = ob; }
                }
                if (fr == 0) {
                    int r = wm + mf * 16 + fq * 4 + j;
                    pbv[(wid & 1) * 128 + r] = best;
                    piv[(wid & 1) * 128 + r] = bi;
                }
            }
        __syncthreads();
        if (tid < 128) {
            float b0 = pbv[tid], b1 = pbv[128 + tid];
            int i0 = piv[tid], i1 = piv[128 + tid];
            idxo[m0 + tid] = (b1 < b0) ? i1 : i0;
        }
        return;
    }

    float bi[4], ga[4], be[4];
#pragma unroll
    for (int nf = 0; nf < 4; ++nf) {
        int col = n0 + wn + nf * 16 + fr;
        bi[nf] = bias[col];
        if (EPI == 1) { ga[nf] = gamma[col]; be[nf] = beta[col]; }
    }
#pragma unroll
    for (int mf = 0; mf < 4; ++mf)
#pragma unroll
        for (int j = 0; j < 4; ++j) {
            long gm = m0 + wm + mf * 16 + fq * 4 + j;
#pragma unroll
            for (int nf = 0; nf < 4; ++nf) {
                int col = n0 + wn + nf * 16 + fr;
                float vv = acc[mf][nf][j] + bi[nf];
                if (EPI == 1) {
                    vv = ga[nf] * (vv * bns) + be[nf];
                    vv = fmaxf(vv, 0.f);
                }
                long o = gm * (long)N + col;
                if (OUTF == 0) {
                    ((float*)oHi)[o] = vv;
                } else if (OUTF == 2) {
                    ((short*)oHi)[o] = (short)bfr(vv);
                } else {
                    unsigned short h = bfr(vv);
                    ((short*)oHi)[o] = (short)h;
                    ((short*)oLo)[o] = (short)bfr(vv - bff(h));
                }
            }
        }
}

__global__ void wprep(const float* __restrict__ w, short* __restrict__ hi,
                      short* __restrict__ lo, int kshift, int total, int N)
{
    int i = blockIdx.x * 256 + threadIdx.x;
    if (i >= total) return;
    int K = 1 << kshift;
    int n = i >> kshift, k = i & (K - 1);
    float x = w[(long)k * N + n];
    unsigned short h = bfr(x);
    hi[i] = (short)h;
    if (lo) lo[i] = (short)bfr(x - bff(h));
}

__global__ void cbprep(const float* __restrict__ cb, short* __restrict__ hi,
                       short* __restrict__ lo)
{
    int i = blockIdx.x * 256 + threadIdx.x;
    float x = cb[i];
    unsigned short h = bfr(x);
    hi[i] = (short)h;
    lo[i] = (short)bfr(x - bff(h));
}

__global__ void rownorm(const float* __restrict__ x, float* __restrict__ o, int rows)
{
    int w = blockIdx.x * (blockDim.x >> 6) + (threadIdx.x >> 6);
    int lane = threadIdx.x & 63;
    if (w >= rows) return;
    const f4* p = (const f4*)(x + (long)w * 1024);
    f4 s = (f4){0.f, 0.f, 0.f, 0.f};
#pragma unroll
    for (int it = 0; it < 4; ++it) {
        f4 v = p[it * 64 + lane];
        s += v * v;
    }
    float t = (s[0] + s[1]) + (s[2] + s[3]);
#pragma unroll
    for (int sh = 32; sh; sh >>= 1) t += __shfl_xor(t, sh, 64);
    if (lane == 0) o[w] = t;
}

__global__ __launch_bounds__(256)
void gather_sq(const float* __restrict__ cb, const int* __restrict__ idx,
               const float* __restrict__ xe, float* __restrict__ q,
               double* __restrict__ part, int rows)
{
    __shared__ double red[256];
    double s = 0.0;
    for (int m = blockIdx.x; m < rows; m += gridDim.x) {
        int c = idx[m];
        const f4* src = (const f4*)(cb + (long)c * 1024);
        const f4* xs  = (const f4*)(xe + (long)m * 1024);
        f4* dst = (f4*)(q + (long)m * 1024);
        f4 v = src[threadIdx.x];
        f4 xv = xs[threadIdx.x];
        dst[threadIdx.x] = v;
        f4 d = v - xv;
        s += ((double)d[0]*d[0] + (double)d[1]*d[1]) + ((double)d[2]*d[2] + (double)d[3]*d[3]);
    }
    red[threadIdx.x] = s; __syncthreads();
    for (int h = 128; h; h >>= 1) {
        if (threadIdx.x < h) red[threadIdx.x] += red[threadIdx.x + h];
        __syncthreads();
    }
    if (threadIdx.x == 0) part[blockIdx.x] = red[0];
}

__global__ void sqdiff_partial(const float* __restrict__ a, const float* __restrict__ b,
                               double* __restrict__ part, long n4)
{
    __shared__ double red[256];
    long i = (long)blockIdx.x * blockDim.x + threadIdx.x;
    long stride = (long)gridDim.x * blockDim.x;
    const f4* A = (const f4*)a;
    const f4* B = (const f4*)b;
    f4 s = (f4){0.f, 0.f, 0.f, 0.f};
    for (; i < n4; i += stride) {
        f4 d = A[i] - B[i];
        s += d * d;
    }
    double t = ((double)s[0] + s[1]) + ((double)s[2] + s[3]);
    red[threadIdx.x] = t;
    __syncthreads();
    for (int h = 128; h; h >>= 1) {
        if (threadIdx.x < h) red[threadIdx.x] += red[threadIdx.x + h];
        __syncthreads();
    }
    if (threadIdx.x == 0) part[blockIdx.x] = red[0];
}

__global__ void finalize_k(const double* __restrict__ pa, int na,
                           const double* __restrict__ pb, int nb,
                           float* __restrict__ loss)
{
    __shared__ double red[256];
    int t = threadIdx.x;
    double sa = 0;
    for (int i = t; i < na; i += 256) sa += pa[i];
    red[t] = sa; __syncthreads();
    for (int h = 128; h; h >>= 1) { if (t < h) red[t] += red[t + h]; __syncthreads(); }
    double SA = red[0];
    __syncthreads();
    double sb = 0;
    for (int i = t; i < nb; i += 256) sb += pb[i];
    red[t] = sb; __syncthreads();
    for (int h = 128; h; h >>= 1) { if (t < h) red[t] += red[t + h]; __syncthreads(); }
    if (t == 0) {
        double recon = SA / 8388608.0;
        double vql = red[0] / 44302336.0;
        loss[0] = (float)(recon + 1.25 * vql);
    }
}

__global__ void vq_mean_k(const float* __restrict__ vqx, const float* __restrict__ mask,
                          float* __restrict__ o)
{
    __shared__ float red[128];
    int b = blockIdx.x;
    int d = threadIdx.x;
    red[d] = mask[b * 256 + d] + mask[b * 256 + 128 + d];
    __syncthreads();
    for (int h = 64; h; h >>= 1) { if (d < h) red[d] += red[d + h]; __syncthreads(); }
    float msum = red[0];
    const float* p = vqx + (long)b * 256 * 128 + d;
    float s = 0.f;
    for (int l = 0; l < 256; ++l) s += p[l * 128];
    o[b * 128 + d] = s / msum;
}

extern "C" void kernel_launch(void* const* d_in, const int* in_sizes, int n_in,
                              void* d_out, int out_size, void* d_ws, size_t ws_size,
                              hipStream_t stream)
{
    const float* x    = (const float*)d_in[0];
    const float* mask = (const float*)d_in[1];
    const float* cb   = (const float*)d_in[2];
    const float* ew1 = (const float*)d_in[3];
    const float* eb1 = (const float*)d_in[4];
    const float* eg1 = (const float*)d_in[5];
    const float* ebt1= (const float*)d_in[6];
    const float* ew2 = (const float*)d_in[7];
    const float* eb2 = (const float*)d_in[8];
    const float* eg2 = (const float*)d_in[9];
    const float* ebt2= (const float*)d_in[10];
    const float* ew3 = (const float*)d_in[11];
    const float* eb3 = (const float*)d_in[12];
    const float* dw1 = (const float*)d_in[13];
    const float* db1 = (const float*)d_in[14];
    const float* dg1 = (const float*)d_in[15];
    const float* dbt1= (const float*)d_in[16];
    const float* dw2 = (const float*)d_in[17];
    const float* db2 = (const float*)d_in[18];
    const float* dg2 = (const float*)d_in[19];
    const float* dbt2= (const float*)d_in[20];
    const float* dw3 = (const float*)d_in[21];
    const float* db3 = (const float*)d_in[22];

    float* out = (float*)d_out;
    float* o_vqmean = out;
    float* o_vqx    = out + 32768;
    float* o_xe     = out + 8421376;
    float* o_q      = out + 52723712;
    float* o_loss   = out + 97026048;

    float* base;
    if (ws_size >= (size_t)WS_FLOATS * 4) {
        base = (float*)d_ws;
    } else {
        void* p = nullptr;
        hipGetSymbolAddress(&p, HIP_SYMBOL(g_fallback));
        base = (float*)p;
    }

    float* cur = base;
    short* h1h = (short*)cur; cur += 7372800;
    short* h1l = (short*)cur; cur += 7372800;
    short* h2h = (short*)cur; cur += 12845056;
    short* h2l = (short*)cur; cur += 12845056;
    short* d1o = (short*)cur; cur += 12845056;
    short* d2o = (short*)cur; cur += 7372800;
    short* ewt1h = (short*)cur; cur += 65536;
    short* ewt1l = (short*)cur; cur += 65536;
    short* ewt2h = (short*)cur; cur += 262144;
    short* ewt2l = (short*)cur; cur += 262144;
    short* ewt3h = (short*)cur; cur += 1048576;
    short* ewt3l = (short*)cur; cur += 1048576;
    short* dwt1h = (short*)cur; cur += 1048576;
    short* dwt2h = (short*)cur; cur += 262144;
    short* dwt3h = (short*)cur; cur += 65536;
    short* cbh   = (short*)cur; cur += 65536;
    short* cbl   = (short*)cur; cur += 65536;
    float* cn = cur; cur += 128;
    int* idxb = (int*)cur; cur += 43264;
    double* pa = (double*)cur; cur += 4096;
    double* pq = (double*)cur; cur += 4096;

    const float bns = (float)(1.0 / sqrt(1.0 + 1e-3));

    wprep<<<512, 256, 0, stream>>>(ew1, ewt1h, ewt1l, 9, 131072, 256);
    wprep<<<2048, 256, 0, stream>>>(ew2, ewt2h, ewt2l, 10, 524288, 512);
    wprep<<<8192, 256, 0, stream>>>(ew3, ewt3h, ewt3l, 11, 2097152, 1024);
    wprep<<<8192, 256, 0, stream>>>(dw1, dwt1h, nullptr, 12, 2097152, 512);
    wprep<<<2048, 256, 0, stream>>>(dw2, dwt2h, nullptr, 11, 524288, 256);
    wprep<<<512, 256, 0, stream>>>(dw3, dwt3h, nullptr, 10, 131072, 128);
    cbprep<<<512, 256, 0, stream>>>(cb, cbh, cbl);
    rownorm<<<32, 256, 0, stream>>>(cb, cn, 128);

    // ---- encoder (bf16x2 split, fp32-grade) ----
    mfma_conv<2, 0, 1, 1><<<dim3(450, 2), 256, 0, stream>>>(
        x, nullptr, nullptr, ewt1h, ewt1l, eb1, eg1, ebt1, h1h, h1l, nullptr,
        16, 16, 128, 7, 225, 15, 256, 512, 0, bns);
    mfma_conv<2, 1, 1, 1><<<dim3(392, 4), 256, 0, stream>>>(
        h1h, h1l, nullptr, ewt2h, ewt2l, eb2, eg2, ebt2, h2h, h2l, nullptr,
        15, 15, 256, 8, 196, 14, 512, 1024, 0, bns);
    mfma_conv<2, 1, 0, 0><<<dim3(338, 8), 256, 0, stream>>>(
        h2h, h2l, nullptr, ewt3h, ewt3l, eb3, nullptr, nullptr, o_xe, nullptr, nullptr,
        14, 14, 512, 9, 169, 13, 1024, 2048, 0, bns);

    // ---- VQ: split-MFMA distance + fused argmin ----
    mfma_conv<2, 0, 2, 0><<<dim3(338, 1), 256, 0, stream>>>(
        o_xe, nullptr, nullptr, cbh, cbl, cn, nullptr, nullptr, nullptr, nullptr, idxb,
        2, 43266, 1024, 10, 43264, 43264, 128, 1024, 0, bns);
    gather_sq<<<2048, 256, 0, stream>>>(cb, idxb, o_xe, o_q, pq, 43264);

    // ---- decoder (plain bf16 MFMA) ----
    mfma_conv<1, 3, 1, 2><<<dim3(392, 4), 256, 0, stream>>>(
        cbh, nullptr, idxb, dwt1h, nullptr, db1, dg1, dbt1, d1o, nullptr, nullptr,
        13, 13, 1024, 10, 196, 14, 512, 4096, -1, bns);
    mfma_conv<1, 2, 1, 2><<<dim3(450, 2), 256, 0, stream>>>(
        d1o, nullptr, nullptr, dwt2h, nullptr, db2, dg2, dbt2, d2o, nullptr, nullptr,
        14, 14, 512, 9, 225, 15, 256, 2048, -1, bns);
    mfma_conv<1, 2, 0, 0><<<dim3(512, 1), 256, 0, stream>>>(
        d2o, nullptr, nullptr, dwt3h, nullptr, db3, nullptr, nullptr, o_vqx, nullptr, nullptr,
        15, 15, 256, 8, 256, 16, 128, 1024, -1, bns);

    // ---- outputs ----
    vq_mean_k<<<256, 128, 0, stream>>>(o_vqx, mask, o_vqmean);
    sqdiff_partial<<<1024, 256, 0, stream>>>(x, o_vqx, pa, 2097152L);
    finalize_k<<<1, 256, 0, stream>>>(pa, 1024, pq, 2048, o_loss);
}

// Round 4
// 1044.793 us; speedup vs baseline: 6.3176x; 1.3330x over previous
//
#include <hip/hip_runtime.h>
#include <math.h>

typedef float f4 __attribute__((ext_vector_type(4)));
typedef short s8 __attribute__((ext_vector_type(8)));

#define WS_FLOATS 66000000L
__device__ float g_fallback[WS_FLOATS];

__device__ __forceinline__ f4 ldg4(const float* p) { return *(const f4*)p; }

__device__ __forceinline__ unsigned short bfr(float x) {   // fp32 -> bf16 RNE
    unsigned int u = __float_as_uint(x);
    u += 0x7fffu + ((u >> 16) & 1u);
    return (unsigned short)(u >> 16);
}
__device__ __forceinline__ float bff(unsigned short h) {
    return __uint_as_float(((unsigned int)h) << 16);
}
__device__ __forceinline__ s8 z8() { s8 z = {0,0,0,0,0,0,0,0}; return z; }

__device__ __forceinline__ void split8(const f4& x0, const f4& x1, s8& hi, s8& lo) {
#pragma unroll
    for (int e = 0; e < 4; ++e) {
        unsigned short h0 = bfr(x0[e]);
        hi[e] = (short)h0; lo[e] = (short)bfr(x0[e] - bff(h0));
        unsigned short h1 = bfr(x1[e]);
        hi[e + 4] = (short)h1; lo[e + 4] = (short)bfr(x1[e] - bff(h1));
    }
}

// ============================================================
// Pipelined MFMA implicit-GEMM conv / convT / VQ-distance.
// SPLIT: 1 = plain bf16 ; 2 = bf16x2 split (3 MFMAs, fp32-grade)
// ASRC : 0 = fp32 (split on the fly) ; 1 = bf16 pair ; 2 = bf16 single
// EPI  : 0 = +bias ; 1 = relu(bn(..)) ; 2 = VQ argmin (bias = dist-bias, -> idxo)
// OUTF : 0 = fp32 ; 1 = bf16 pair ; 2 = bf16 single
// ============================================================
template<int SPLIT, int ASRC, int EPI, int OUTF>
__global__ __launch_bounds__(256, 2)
void mfma_conv(const void* __restrict__ aHi, const void* __restrict__ aLo,
               const short* __restrict__ wHi, const short* __restrict__ wLo,
               const float* __restrict__ bias, const float* __restrict__ gamma,
               const float* __restrict__ beta,
               void* __restrict__ oHi, void* __restrict__ oLo,
               int* __restrict__ idxo,
               int IH, int IW, int Cin, int cinShift, int OHOW, int OW,
               int N, int K, int off, float bns)
{
    constexpr int PL = 128 * 64;
    __shared__ short smem[2 * SPLIT * PL];
    short* Ah = smem;
    short* Al = smem + PL;
    short* Bh = smem + SPLIT * PL;
    short* Bl = smem + SPLIT * PL + PL;

    const int tid = threadIdx.x;
    const int lane = tid & 63, wid = tid >> 6;
    const int fr = lane & 15, fq = lane >> 4;
    const int wm = (wid >> 1) * 64, wn = (wid & 1) * 64;
    const int m0 = blockIdx.x * 128, n0 = blockIdx.y * 128;

    const int sr = tid >> 1;
    const int skh = (tid & 1) << 5;

    long tapOff[4]; bool tv[4];
    {
        int m = m0 + sr;
        int b = m / OHOW; int rem = m - b * OHOW;
        int oi = rem / OW; int oj = rem - oi * OW;
#pragma unroll
        for (int t = 0; t < 4; ++t) {
            int ii = oi + (t >> 1) + off, jj = oj + (t & 1) + off;
            bool v = (ii >= 0) && (ii < IH) && (jj >= 0) && (jj < IW);
            tv[t] = v;
            tapOff[t] = ((long)b * IH + (v ? ii : 0)) * IW + (v ? jj : 0);
        }
    }

    f4 acc[4][4];
#pragma unroll
    for (int a = 0; a < 4; ++a)
#pragma unroll
        for (int b = 0; b < 4; ++b) acc[a][b] = (f4){0.f, 0.f, 0.f, 0.f};

    const short* wHrow = wHi + (long)(n0 + sr) * K;
    const short* wLrow = (SPLIT == 2) ? (wLo + (long)(n0 + sr) * K) : nullptr;

    const int swzW = (sr & 7) << 3;
    const int sbase = sr * 64;

    s8 rah[4], ral[4], rbh[4], rbl[4];
    f4 rax0[4], rax1[4];

    auto LOADREGS = [&](int kc) {
        const int kk = kc + skh;
        const int t = kk >> cinShift;
        const int ci = kk & (Cin - 1);
        const bool v = tv[t];
        if (ASRC == 0) {
            const float* p = (const float*)aHi + tapOff[t] * Cin + ci;
#pragma unroll
            for (int q = 0; q < 4; ++q) {
                rax0[q] = v ? ldg4(p + 8 * q) : (f4){0.f,0.f,0.f,0.f};
                rax1[q] = v ? ldg4(p + 8 * q + 4) : (f4){0.f,0.f,0.f,0.f};
            }
        } else if (ASRC == 1) {
            const short* ph = (const short*)aHi + tapOff[t] * Cin + ci;
            const short* pl = (const short*)aLo + tapOff[t] * Cin + ci;
#pragma unroll
            for (int q = 0; q < 4; ++q) {
                rah[q] = v ? *(const s8*)(ph + 8 * q) : z8();
                ral[q] = v ? *(const s8*)(pl + 8 * q) : z8();
            }
        } else {
            const short* ph = (const short*)aHi + tapOff[t] * Cin + ci;
#pragma unroll
            for (int q = 0; q < 4; ++q) rah[q] = v ? *(const s8*)(ph + 8 * q) : z8();
        }
#pragma unroll
        for (int q = 0; q < 4; ++q) {
            rbh[q] = *(const s8*)(wHrow + kc + skh + 8 * q);
            if (SPLIT == 2) rbl[q] = *(const s8*)(wLrow + kc + skh + 8 * q);
        }
    };

    auto STORE = [&]() {
        if (ASRC == 0) {
#pragma unroll
            for (int q = 0; q < 4; ++q) split8(rax0[q], rax1[q], rah[q], ral[q]);
        }
#pragma unroll
        for (int q = 0; q < 4; ++q) {
            int kx = (skh + 8 * q) ^ swzW;
            *(s8*)&Ah[sbase + kx] = rah[q];
            if (SPLIT == 2) *(s8*)&Al[sbase + kx] = ral[q];
            *(s8*)&Bh[sbase + kx] = rbh[q];
            if (SPLIT == 2) *(s8*)&Bl[sbase + kx] = rbl[q];
        }
    };

    LOADREGS(0);
    for (int kc = 0; kc < K; kc += 64) {
        __syncthreads();
        STORE();
        __syncthreads();
        if (kc + 64 < K) LOADREGS(kc + 64);

        __builtin_amdgcn_s_setprio(1);
#pragma unroll
        for (int ks = 0; ks < 2; ++ks) {
            const int colk = ks * 32 + fq * 8;
            s8 afh[4], afl[4], bfh[4], bfl[4];
#pragma unroll
            for (int mf = 0; mf < 4; ++mf) {
                int ar = wm + mf * 16 + fr;
                int ai = ar * 64 + (colk ^ ((ar & 7) << 3));
                afh[mf] = *(const s8*)&Ah[ai];
                if (SPLIT == 2) afl[mf] = *(const s8*)&Al[ai];
            }
#pragma unroll
            for (int nf = 0; nf < 4; ++nf) {
                int br = wn + nf * 16 + fr;
                int bi2 = br * 64 + (colk ^ ((br & 7) << 3));
                bfh[nf] = *(const s8*)&Bh[bi2];
                if (SPLIT == 2) bfl[nf] = *(const s8*)&Bl[bi2];
            }
#pragma unroll
            for (int mf = 0; mf < 4; ++mf)
#pragma unroll
                for (int nf = 0; nf < 4; ++nf) {
                    acc[mf][nf] = __builtin_amdgcn_mfma_f32_16x16x32_bf16(
                        afh[mf], bfh[nf], acc[mf][nf], 0, 0, 0);
                    if (SPLIT == 2) {
                        acc[mf][nf] = __builtin_amdgcn_mfma_f32_16x16x32_bf16(
                            afh[mf], bfl[nf], acc[mf][nf], 0, 0, 0);
                        acc[mf][nf] = __builtin_amdgcn_mfma_f32_16x16x32_bf16(
                            afl[mf], bfh[nf], acc[mf][nf], 0, 0, 0);
                    }
                }
        }
        __builtin_amdgcn_s_setprio(0);
    }

    if (EPI == 2) {
        // dist (mod row-const) = bias[col] - 2*acc ; argmin over 128 cols
        __syncthreads();
        float* pbv = (float*)smem;
        int*   piv = (int*)((float*)smem + 256);
        float cnv[4];
#pragma unroll
        for (int nf = 0; nf < 4; ++nf) cnv[nf] = bias[n0 + wn + nf * 16 + fr];
#pragma unroll
        for (int mf = 0; mf < 4; ++mf)
#pragma unroll
            for (int j = 0; j < 4; ++j) {
                float best = 3.4e38f; int bi = 0;
#pragma unroll
                for (int nf = 0; nf < 4; ++nf) {
                    float d = cnv[nf] - 2.0f * acc[mf][nf][j];
                    int col = wn + nf * 16 + fr;
                    if (d < best) { best = d; bi = col; }
                }
#pragma unroll
                for (int sh = 1; sh <= 8; sh <<= 1) {
                    float ov = __shfl_xor(best, sh, 64);
                    int ob = __shfl_xor(bi, sh, 64);
                    if (ov < best || (ov == best && ob < bi)) { best = ov; bi = ob; }
                }
                if (fr == 0) {
                    int r = wm + mf * 16 + fq * 4 + j;
                    pbv[(wid & 1) * 128 + r] = best;
                    piv[(wid & 1) * 128 + r] = bi;
                }
            }
        __syncthreads();
        if (tid < 128) {
            float b0 = pbv[tid], b1 = pbv[128 + tid];
            int i0 = piv[tid], i1 = piv[128 + tid];
            idxo[m0 + tid] = (b1 < b0) ? i1 : i0;
        }
        return;
    }

    float bi[4], ga[4], be[4];
#pragma unroll
    for (int nf = 0; nf < 4; ++nf) {
        int col = n0 + wn + nf * 16 + fr;
        bi[nf] = bias[col];
        if (EPI == 1) { ga[nf] = gamma[col]; be[nf] = beta[col]; }
    }
#pragma unroll
    for (int mf = 0; mf < 4; ++mf)
#pragma unroll
        for (int j = 0; j < 4; ++j) {
            long gm = m0 + wm + mf * 16 + fq * 4 + j;
#pragma unroll
            for (int nf = 0; nf < 4; ++nf) {
                int col = n0 + wn + nf * 16 + fr;
                float vv = acc[mf][nf][j] + bi[nf];
                if (EPI == 1) {
                    vv = ga[nf] * (vv * bns) + be[nf];
                    vv = fmaxf(vv, 0.f);
                }
                long o = gm * (long)N + col;
                if (OUTF == 0) {
                    ((float*)oHi)[o] = vv;
                } else if (OUTF == 2) {
                    ((short*)oHi)[o] = (short)bfr(vv);
                } else {
                    unsigned short h = bfr(vv);
                    ((short*)oHi)[o] = (short)h;
                    ((short*)oLo)[o] = (short)bfr(vv - bff(h));
                }
            }
        }
}

// ---- weight prep: [K][N] fp32 -> [N][K] bf16 hi (,lo) ----
__global__ void wprep(const float* __restrict__ w, short* __restrict__ hi,
                      short* __restrict__ lo, int kshift, int total, int N)
{
    int i = blockIdx.x * 256 + threadIdx.x;
    if (i >= total) return;
    int K = 1 << kshift;
    int n = i >> kshift, k = i & (K - 1);
    float x = w[(long)k * N + n];
    unsigned short h = bfr(x);
    hi[i] = (short)h;
    if (lo) lo[i] = (short)bfr(x - bff(h));
}

// dw1 [4][1024][512] -> [N'=t*512+n][co=1024] bf16 hi/lo
__global__ void dw1Tprep(const float* __restrict__ w, short* __restrict__ hi,
                         short* __restrict__ lo)
{
    int i = blockIdx.x * 256 + threadIdx.x;
    if (i >= 2097152) return;
    int Np = i >> 10, co = i & 1023;
    int t = Np >> 9, nn = Np & 511;
    float x = w[((long)(t * 1024 + co)) * 512 + nn];
    unsigned short h = bfr(x);
    hi[i] = (short)h;
    lo[i] = (short)bfr(x - bff(h));
}

__global__ void cbprep(const float* __restrict__ cb, short* __restrict__ hi,
                       short* __restrict__ lo)
{
    int i = blockIdx.x * 256 + threadIdx.x;
    float x = cb[i];
    unsigned short h = bfr(x);
    hi[i] = (short)h;
    lo[i] = (short)bfr(x - bff(h));
}

// P1raw [k=2048][n=128] fp32 -> wv [n][k] bf16 hi/lo
__global__ void wsplitT(const float* __restrict__ p1, short* __restrict__ hi,
                        short* __restrict__ lo)
{
    int i = blockIdx.x * 256 + threadIdx.x;
    if (i >= 262144) return;
    int n = i >> 11, k = i & 2047;
    float x = p1[(long)k * 128 + n];
    unsigned short h = bfr(x);
    hi[i] = (short)h;
    lo[i] = (short)bfr(x - bff(h));
}

// bias2[c] = ||cb_c||^2 - 2*dot(eb3, cb_c)
__global__ void code_bias(const float* __restrict__ cb, const float* __restrict__ eb3,
                          float* __restrict__ bias2)
{
    int c = blockIdx.x * 4 + (threadIdx.x >> 6);
    int lane = threadIdx.x & 63;
    if (c >= 128) return;
    const f4* p = (const f4*)(cb + (long)c * 1024);
    const f4* e = (const f4*)eb3;
    float s2 = 0.f, su = 0.f;
#pragma unroll
    for (int q = 0; q < 4; ++q) {
        f4 v = p[q * 64 + lane];
        f4 w = e[q * 64 + lane];
        s2 += (v[0]*v[0] + v[1]*v[1]) + (v[2]*v[2] + v[3]*v[3]);
        su += (v[0]*w[0] + v[1]*w[1]) + (v[2]*w[2] + v[3]*w[3]);
    }
#pragma unroll
    for (int sh = 32; sh; sh >>= 1) {
        s2 += __shfl_xor(s2, sh, 64);
        su += __shfl_xor(su, sh, 64);
    }
    if (lane == 0) bias2[c] = s2 - 2.f * su;
}

// D1 via folded codebook table: out[m,n] = relu(bn(sum_t CD[c_t, t*512+n] + db1))
__global__ __launch_bounds__(256)
void d1_gather(const float* __restrict__ CD, const int* __restrict__ idx,
               const float* __restrict__ db1, const float* __restrict__ dg1,
               const float* __restrict__ dbt1, short* __restrict__ out, float bns)
{
    int m = blockIdx.x * 4 + (threadIdx.x >> 6);
    int lane = threadIdx.x & 63;
    if (m >= 50176) return;
    int b = m / 196, rem = m - b * 196;
    int oi = rem / 14, oj = rem - oi * 14;
    float2 acc[4];
#pragma unroll
    for (int q = 0; q < 4; ++q) acc[q] = make_float2(0.f, 0.f);
#pragma unroll
    for (int t = 0; t < 4; ++t) {
        int ii = oi - 1 + (t >> 1), jj = oj - 1 + (t & 1);
        if (ii >= 0 && ii < 13 && jj >= 0 && jj < 13) {
            int c = idx[(b * 13 + ii) * 13 + jj];
            const float2* p = (const float2*)(CD + ((long)c * 2048 + t * 512));
#pragma unroll
            for (int q = 0; q < 4; ++q) {
                float2 v = p[lane + 64 * q];
                acc[q].x += v.x; acc[q].y += v.y;
            }
        }
    }
#pragma unroll
    for (int q = 0; q < 4; ++q) {
        int n = 2 * (lane + 64 * q);
        float v0 = fmaxf(dg1[n]     * ((acc[q].x + db1[n])     * bns) + dbt1[n],     0.f);
        float v1 = fmaxf(dg1[n + 1] * ((acc[q].y + db1[n + 1]) * bns) + dbt1[n + 1], 0.f);
        short2 s2v;
        s2v.x = (short)bfr(v0); s2v.y = (short)bfr(v1);
        ((short2*)out)[(long)m * 256 + lane + 64 * q] = s2v;
    }
}

__global__ __launch_bounds__(256)
void gather_sq(const float* __restrict__ cb, const int* __restrict__ idx,
               const float* __restrict__ xe, float* __restrict__ q,
               double* __restrict__ part, int rows)
{
    __shared__ double red[256];
    double s = 0.0;
    for (int m = blockIdx.x; m < rows; m += gridDim.x) {
        int c = idx[m];
        const f4* src = (const f4*)(cb + (long)c * 1024);
        const f4* xs  = (const f4*)(xe + (long)m * 1024);
        f4* dst = (f4*)(q + (long)m * 1024);
        f4 v = src[threadIdx.x];
        f4 xv = xs[threadIdx.x];
        dst[threadIdx.x] = v;
        f4 d = v - xv;
        s += ((double)d[0]*d[0] + (double)d[1]*d[1]) + ((double)d[2]*d[2] + (double)d[3]*d[3]);
    }
    red[threadIdx.x] = s; __syncthreads();
    for (int h = 128; h; h >>= 1) {
        if (threadIdx.x < h) red[threadIdx.x] += red[threadIdx.x + h];
        __syncthreads();
    }
    if (threadIdx.x == 0) part[blockIdx.x] = red[0];
}

__global__ void sqdiff_partial(const float* __restrict__ a, const float* __restrict__ b,
                               double* __restrict__ part, long n4)
{
    __shared__ double red[256];
    long i = (long)blockIdx.x * blockDim.x + threadIdx.x;
    long stride = (long)gridDim.x * blockDim.x;
    const f4* A = (const f4*)a;
    const f4* B = (const f4*)b;
    f4 s = (f4){0.f, 0.f, 0.f, 0.f};
    for (; i < n4; i += stride) {
        f4 d = A[i] - B[i];
        s += d * d;
    }
    double t = ((double)s[0] + s[1]) + ((double)s[2] + s[3]);
    red[threadIdx.x] = t;
    __syncthreads();
    for (int h = 128; h; h >>= 1) {
        if (threadIdx.x < h) red[threadIdx.x] += red[threadIdx.x + h];
        __syncthreads();
    }
    if (threadIdx.x == 0) part[blockIdx.x] = red[0];
}

__global__ void finalize_k(const double* __restrict__ pa, int na,
                           const double* __restrict__ pb, int nb,
                           float* __restrict__ loss)
{
    __shared__ double red[256];
    int t = threadIdx.x;
    double sa = 0;
    for (int i = t; i < na; i += 256) sa += pa[i];
    red[t] = sa; __syncthreads();
    for (int h = 128; h; h >>= 1) { if (t < h) red[t] += red[t + h]; __syncthreads(); }
    double SA = red[0];
    __syncthreads();
    double sb = 0;
    for (int i = t; i < nb; i += 256) sb += pb[i];
    red[t] = sb; __syncthreads();
    for (int h = 128; h; h >>= 1) { if (t < h) red[t] += red[t + h]; __syncthreads(); }
    if (t == 0) {
        double recon = SA / 8388608.0;
        double vql = red[0] / 44302336.0;
        loss[0] = (float)(recon + 1.25 * vql);
    }
}

__global__ void vq_mean_k(const float* __restrict__ vqx, const float* __restrict__ mask,
                          float* __restrict__ o)
{
    __shared__ float red[128];
    int b = blockIdx.x;
    int d = threadIdx.x;
    red[d] = mask[b * 256 + d] + mask[b * 256 + 128 + d];
    __syncthreads();
    for (int h = 64; h; h >>= 1) { if (d < h) red[d] += red[d + h]; __syncthreads(); }
    float msum = red[0];
    const float* p = vqx + (long)b * 256 * 128 + d;
    float s = 0.f;
    for (int l = 0; l < 256; ++l) s += p[l * 128];
    o[b * 128 + d] = s / msum;
}

extern "C" void kernel_launch(void* const* d_in, const int* in_sizes, int n_in,
                              void* d_out, int out_size, void* d_ws, size_t ws_size,
                              hipStream_t stream)
{
    const float* x    = (const float*)d_in[0];
    const float* mask = (const float*)d_in[1];
    const float* cb   = (const float*)d_in[2];
    const float* ew1 = (const float*)d_in[3];
    const float* eb1 = (const float*)d_in[4];
    const float* eg1 = (const float*)d_in[5];
    const float* ebt1= (const float*)d_in[6];
    const float* ew2 = (const float*)d_in[7];
    const float* eb2 = (const float*)d_in[8];
    const float* eg2 = (const float*)d_in[9];
    const float* ebt2= (const float*)d_in[10];
    const float* ew3 = (const float*)d_in[11];
    const float* eb3 = (const float*)d_in[12];
    const float* dw1 = (const float*)d_in[13];
    const float* db1 = (const float*)d_in[14];
    const float* dg1 = (const float*)d_in[15];
    const float* dbt1= (const float*)d_in[16];
    const float* dw2 = (const float*)d_in[17];
    const float* db2 = (const float*)d_in[18];
    const float* dg2 = (const float*)d_in[19];
    const float* dbt2= (const float*)d_in[20];
    const float* dw3 = (const float*)d_in[21];
    const float* db3 = (const float*)d_in[22];

    float* out = (float*)d_out;
    float* o_vqmean = out;
    float* o_vqx    = out + 32768;
    float* o_xe     = out + 8421376;
    float* o_q      = out + 52723712;
    float* o_loss   = out + 97026048;

    float* base;
    if (ws_size >= (size_t)WS_FLOATS * 4) {
        base = (float*)d_ws;
    } else {
        void* p = nullptr;
        hipGetSymbolAddress(&p, HIP_SYMBOL(g_fallback));
        base = (float*)p;
    }

    float* cur = base;
    short* h1h = (short*)cur; cur += 7372800;
    short* h1l = (short*)cur; cur += 7372800;
    short* h2h = (short*)cur; cur += 12845056;
    short* h2l = (short*)cur; cur += 12845056;
    short* d1o = (short*)cur; cur += 12845056;
    short* d2o = (short*)cur; cur += 7372800;
    short* ewt1h = (short*)cur; cur += 65536;
    short* ewt1l = (short*)cur; cur += 65536;
    short* ewt2h = (short*)cur; cur += 262144;
    short* ewt2l = (short*)cur; cur += 262144;
    short* ewt3h = (short*)cur; cur += 1048576;
    short* dwt1Th = (short*)cur; cur += 1048576;
    short* dwt1Tl = (short*)cur; cur += 1048576;
    short* dwt2h = (short*)cur; cur += 262144;
    short* dwt3h = (short*)cur; cur += 65536;
    short* cbh   = (short*)cur; cur += 65536;
    short* cbl   = (short*)cur; cur += 65536;
    float* P1raw = cur; cur += 262144;
    short* wvh   = (short*)cur; cur += 131072;
    short* wvl   = (short*)cur; cur += 131072;
    float* CDt   = cur; cur += 262144;
    float* bias2 = cur; cur += 128;
    float* zbuf  = cur; cur += 2048;
    int* idxb = (int*)cur; cur += 43264;
    double* pa = (double*)cur; cur += 4096;
    double* pq = (double*)cur; cur += 4096;

    const float bns = (float)(1.0 / sqrt(1.0 + 1e-3));

    // ---- prep ----
    hipMemsetAsync(zbuf, 0, 2048 * sizeof(float), stream);
    wprep<<<512, 256, 0, stream>>>(ew1, ewt1h, ewt1l, 9, 131072, 256);
    wprep<<<2048, 256, 0, stream>>>(ew2, ewt2h, ewt2l, 10, 524288, 512);
    wprep<<<8192, 256, 0, stream>>>(ew3, ewt3h, nullptr, 11, 2097152, 1024);
    dw1Tprep<<<8192, 256, 0, stream>>>(dw1, dwt1Th, dwt1Tl);
    wprep<<<2048, 256, 0, stream>>>(dw2, dwt2h, nullptr, 11, 524288, 256);
    wprep<<<512, 256, 0, stream>>>(dw3, dwt3h, nullptr, 10, 131072, 128);
    cbprep<<<512, 256, 0, stream>>>(cb, cbh, cbl);
    code_bias<<<32, 256, 0, stream>>>(cb, eb3, bias2);

    // ---- folds ----
    // P1raw[k=t*512+ci][n] = sum_co ew3[t,ci,co] * cb[n,co]   (M=2048,K=1024,N=128)
    mfma_conv<2, 0, 0, 0><<<dim3(16, 1), 256, 0, stream>>>(
        ew3, nullptr, cbh, cbl, zbuf, nullptr, nullptr, P1raw, nullptr, nullptr,
        2, 2050, 1024, 10, 2048, 2048, 128, 1024, 0, bns);
    wsplitT<<<1024, 256, 0, stream>>>(P1raw, wvh, wvl);
    // CD[c][t*512+n] = sum_co cb[c,co] * dw1[t,co,n]          (M=128,K=1024,N=2048)
    mfma_conv<2, 0, 0, 0><<<dim3(1, 16), 256, 0, stream>>>(
        cb, nullptr, dwt1Th, dwt1Tl, zbuf, nullptr, nullptr, CDt, nullptr, nullptr,
        2, 130, 1024, 10, 128, 128, 2048, 1024, 0, bns);

    // ---- encoder ----
    mfma_conv<2, 0, 1, 1><<<dim3(450, 2), 256, 0, stream>>>(
        x, nullptr, ewt1h, ewt1l, eb1, eg1, ebt1, h1h, h1l, nullptr,
        16, 16, 128, 7, 225, 15, 256, 512, 0, bns);
    mfma_conv<2, 1, 1, 1><<<dim3(392, 4), 256, 0, stream>>>(
        h1h, h1l, ewt2h, ewt2l, eb2, eg2, ebt2, h2h, h2l, nullptr,
        15, 15, 256, 8, 196, 14, 512, 1024, 0, bns);
    // x_encode output: plain bf16 (fast path; argmin uses the folded route)
    mfma_conv<1, 2, 0, 0><<<dim3(338, 8), 256, 0, stream>>>(
        h2h, nullptr, ewt3h, nullptr, eb3, nullptr, nullptr, o_xe, nullptr, nullptr,
        14, 14, 512, 9, 169, 13, 1024, 2048, 0, bns);

    // ---- VQ: dist via folded W3c (split, fp32-grade) + fused argmin ----
    mfma_conv<2, 1, 2, 0><<<dim3(338, 1), 256, 0, stream>>>(
        h2h, h2l, wvh, wvl, bias2, nullptr, nullptr, nullptr, nullptr, idxb,
        14, 14, 512, 9, 169, 13, 128, 2048, 0, bns);
    gather_sq<<<2048, 256, 0, stream>>>(cb, idxb, o_xe, o_q, pq, 43264);

    // ---- decoder ----
    d1_gather<<<12544, 256, 0, stream>>>(CDt, idxb, db1, dg1, dbt1, d1o, bns);
    mfma_conv<1, 2, 1, 2><<<dim3(450, 2), 256, 0, stream>>>(
        d1o, nullptr, dwt2h, nullptr, db2, dg2, dbt2, d2o, nullptr, nullptr,
        14, 14, 512, 9, 225, 15, 256, 2048, -1, bns);
    mfma_conv<1, 2, 0, 0><<<dim3(512, 1), 256, 0, stream>>>(
        d2o, nullptr, dwt3h, nullptr, db3, nullptr, nullptr, o_vqx, nullptr, nullptr,
        15, 15, 256, 8, 256, 16, 128, 1024, -1, bns);

    // ---- outputs ----
    vq_mean_k<<<256, 128, 0, stream>>>(o_vqx, mask, o_vqmean);
    sqdiff_partial<<<1024, 256, 0, stream>>>(x, o_vqx, pa, 2097152L);
    finalize_k<<<1, 256, 0, stream>>>(pa, 1024, pq, 2048, o_loss);
}